// Round 4
// baseline (150.173 us; speedup 1.0000x reference)
//
#include <hip/hip_runtime.h>
#include <math.h>

#define IMG_W 512
#define IMG_H 512
#define NIMG 16
#define HWSZ (IMG_W * IMG_H)          // 262144
#define CHWSZ (3 * HWSZ)              // 786432
#define NORM (1.0 / 4194304.0)        // 1 / (N*H*W)
#define RING 24                       // LDS ring rows (max live span = 24)
#define NBLK 256                      // 16 images x 16 h-segments

__device__ __forceinline__ float f_lab(float t) {
    float c = exp2f(log2f(t) * (1.0f / 3.0f));   // cbrt; small-t branch selected away
    return (t > 0.008856f) ? c : fmaf(7.787f, t, 0.13793103448275862f);
}

__device__ __forceinline__ void rgb_to_luv(float r, float g, float b,
                                           float& l, float& u, float& v) {
    float x = 0.4124564f * r + 0.3575761f * g + 0.1804375f * b;
    float y = 0.2126729f * r + 0.7151522f * g + 0.0721750f * b;
    float z = 0.0193339f * r + 0.1191920f * g + 0.9503041f * b;
    x *= (1.0f / 0.95047f);
    z *= (1.0f / 1.08883f);
    float fx = f_lab(x), fy = f_lab(y), fz = f_lab(z);
    l = 116.0f * fy - 16.0f;
    u = 13.0f * l * (fx - fy);
    v = 13.0f * l * (fy - fz);
}

__device__ __forceinline__ unsigned short f2bf(float x) {   // RNE f32->bf16
    unsigned int u = __float_as_uint(x);
    u += 0x7fff + ((u >> 16) & 1);
    return (unsigned short)(u >> 16);
}
__device__ __forceinline__ float bf2f(unsigned short u) {
    return __uint_as_float((unsigned)u << 16);
}

// 15-tap horizontal sliding window across a wave-owned 512-px row (8 px/lane);
// halo via lane shuffles, zero padding at row ends. (validated R3)
__device__ __forceinline__ void hslide(const float d[8], float o[8], int lane) {
    float L[7], R[7];
    #pragma unroll
    for (int j = 0; j < 7; ++j) {
        float l = __shfl_up(d[j + 1], 1, 64);
        L[j] = (lane == 0) ? 0.0f : l;
        float r = __shfl_down(d[j], 1, 64);
        R[j] = (lane == 63) ? 0.0f : r;
    }
    float s = 0.0f;
    #pragma unroll
    for (int j = 0; j < 7; ++j) s += L[j];
    #pragma unroll
    for (int j = 0; j < 8; ++j) s += d[j];
    o[0] = s;
    #pragma unroll
    for (int k = 1; k < 8; ++k) o[k] = o[k - 1] + R[k - 1] - L[k - 1];
}

__device__ __forceinline__ uint4 pack8(const float o[8]) {
    uint4 p;
    p.x = (unsigned)f2bf(o[0]) | ((unsigned)f2bf(o[1]) << 16);
    p.y = (unsigned)f2bf(o[2]) | ((unsigned)f2bf(o[3]) << 16);
    p.z = (unsigned)f2bf(o[4]) | ((unsigned)f2bf(o[5]) << 16);
    p.w = (unsigned)f2bf(o[6]) | ((unsigned)f2bf(o[7]) << 16);
    return p;
}

__device__ __forceinline__ void load6(const float* __restrict__ p, size_t base,
                                      float4 v[6]) {
    v[0] = *(const float4*)(p + base);
    v[1] = *(const float4*)(p + base + 4);
    v[2] = *(const float4*)(p + base + HWSZ);
    v[3] = *(const float4*)(p + base + HWSZ + 4);
    v[4] = *(const float4*)(p + base + 2 * HWSZ);
    v[5] = *(const float4*)(p + base + 2 * HWSZ + 4);
}

// LUV diff + h-pass one row from preloaded regs -> bf16 ring row (zeros if !valid)
__device__ __forceinline__ void row_to_ring(const float4 vi[6], const float4 vt[6],
        bool valid, unsigned short (*ring)[3][IMG_W], int slot, int lane) {
    int w0 = lane << 3;
    if (valid) {
        float R[8], G[8], B[8], dl[8], du[8], dv[8];
        *(float4*)&R[0] = vi[0]; *(float4*)&R[4] = vi[1];
        *(float4*)&G[0] = vi[2]; *(float4*)&G[4] = vi[3];
        *(float4*)&B[0] = vi[4]; *(float4*)&B[4] = vi[5];
        #pragma unroll
        for (int j = 0; j < 8; ++j)
            rgb_to_luv(R[j], G[j], B[j], dl[j], du[j], dv[j]);
        *(float4*)&R[0] = vt[0]; *(float4*)&R[4] = vt[1];
        *(float4*)&G[0] = vt[2]; *(float4*)&G[4] = vt[3];
        *(float4*)&B[0] = vt[4]; *(float4*)&B[4] = vt[5];
        #pragma unroll
        for (int j = 0; j < 8; ++j) {
            float l2, u2, v2;
            rgb_to_luv(R[j], G[j], B[j], l2, u2, v2);
            dl[j] -= l2; du[j] -= u2; dv[j] -= v2;
        }
        float o[8];
        hslide(dl, o, lane); *(uint4*)&ring[slot][0][w0] = pack8(o);
        hslide(du, o, lane); *(uint4*)&ring[slot][1][w0] = pack8(o);
        hslide(dv, o, lane); *(uint4*)&ring[slot][2][w0] = pack8(o);
    } else {
        uint4 z = make_uint4(0u, 0u, 0u, 0u);
        *(uint4*)&ring[slot][0][w0] = z;
        *(uint4*)&ring[slot][1][w0] = z;
        *(uint4*)&ring[slot][2][w0] = z;
    }
}

// Fully fused: LUV diff + 15x15 box (separable) + squared-sum reduction.
// Block = 8 waves; handles 32 output rows of one image. Waves produce h-passed
// rows (8/group) into a 24-row LDS ring; 512 threads each own 1 column x 3 ch
// of the vertical running window. Next group's global loads are issued BEFORE
// the consume phase (T14) so HBM stays busy through LDS phases.
__global__ __launch_bounds__(512) void fused_luv_box(
        const float* __restrict__ inp, const float* __restrict__ tgt,
        float* __restrict__ partial) {
    __shared__ unsigned short ring[RING][3][IMG_W];   // 72 KB
    __shared__ float red[8];
    int blk = blockIdx.x;
    int n = blk >> 4;
    int h0 = (blk & 15) << 5;            // 32 output rows h0..h0+31
    int t = (int)threadIdx.x;
    int wid = t >> 6, lane = t & 63;
    int w0 = lane << 3;
    size_t nb = (size_t)n * CHWSZ + w0;

    // ---- prologue: produce rel rows 0..23 (groups G0,G1,G2; rel = row-(h0-7)) ----
    float4 xa[6], xb[6], ya[6], yb[6];
    int pr0 = h0 - 7 + wid;              // G0: may be <0 at hseg 0
    int pr1 = pr0 + 8, pr2 = pr0 + 16;   // always in [1,496] -> valid
    bool v0 = (pr0 >= 0);
    if (v0) { load6(inp, nb + (size_t)pr0 * IMG_W, xa);
              load6(tgt, nb + (size_t)pr0 * IMG_W, xb); }
    load6(inp, nb + (size_t)pr1 * IMG_W, ya);
    load6(tgt, nb + (size_t)pr1 * IMG_W, yb);
    row_to_ring(xa, xb, v0, ring, wid, lane);
    load6(inp, nb + (size_t)pr2 * IMG_W, xa);
    load6(tgt, nb + (size_t)pr2 * IMG_W, xb);
    row_to_ring(ya, yb, true, ring, 8 + wid, lane);
    row_to_ring(xa, xb, true, ring, 16 + wid, lane);
    __syncthreads();

    // ---- prime vertical window: rel rows 0..14 (= global h0-7..h0+7) ----
    int col = t;
    float Wl = 0.f, Wu = 0.f, Wv = 0.f;
    #pragma unroll
    for (int r = 0; r < 15; ++r) {
        Wl += bf2f(ring[r][0][col]);
        Wu += bf2f(ring[r][1][col]);
        Wv += bf2f(ring[r][2][col]);
    }

    float acc = 0.f;
    // ---- main: 4 iterations x {issue loads G(3+b); consume 8 rows; write ring} ----
    #pragma unroll
    for (int b = 0; b < 4; ++b) {
        bool hasG = (b < 3);
        int pr = h0 + 17 + 8 * b + wid;                  // G(3+b) global row
        bool gv = hasG && (pr < IMG_H) && (b < 2 || wid < 6);  // G5 has 6 rows
        if (gv) { load6(inp, nb + (size_t)pr * IMG_W, xa);
                  load6(tgt, nb + (size_t)pr * IMG_W, xb); }
        #pragma unroll
        for (int j = 0; j < 8; ++j) {
            int i = 8 * b + j;                           // output row h0+i
            acc += Wl * Wl + Wu * Wu + Wv * Wv;
            if (i < 31) {                                // advance window
                int sA = (i + 15) % 24, sS = i % 24;
                Wl += bf2f(ring[sA][0][col]) - bf2f(ring[sS][0][col]);
                Wu += bf2f(ring[sA][1][col]) - bf2f(ring[sS][1][col]);
                Wv += bf2f(ring[sA][2][col]) - bf2f(ring[sS][2][col]);
            }
        }
        __syncthreads();                                 // consume done before overwrite
        if (hasG) row_to_ring(xa, xb, gv, ring, 8 * b + wid, lane);
        __syncthreads();
    }

    // ---- block reduction ----
    #pragma unroll
    for (int off = 32; off > 0; off >>= 1)
        acc += __shfl_down(acc, off, 64);
    if (lane == 0) red[wid] = acc;
    __syncthreads();
    if (t == 0) {
        float s = 0.f;
        #pragma unroll
        for (int k = 0; k < 8; ++k) s += red[k];
        partial[blk] = s;
    }
}

__global__ __launch_bounds__(256) void finalize4(
        const float* __restrict__ partial, float* __restrict__ out) {
    int t = (int)threadIdx.x;
    float a = partial[t];                                // NBLK == 256
    #pragma unroll
    for (int off = 32; off > 0; off >>= 1)
        a += __shfl_down(a, off, 64);
    __shared__ float red[4];
    int lane = t & 63, wid = t >> 6;
    if (lane == 0) red[wid] = a;
    __syncthreads();
    if (t == 0)
        out[0] = (float)((double)(red[0] + red[1] + red[2] + red[3]) * NORM);
}

extern "C" void kernel_launch(void* const* d_in, const int* in_sizes, int n_in,
                              void* d_out, int out_size, void* d_ws, size_t ws_size,
                              hipStream_t stream) {
    const float* inp = (const float*)d_in[0];
    const float* tgt = (const float*)d_in[1];
    float* out = (float*)d_out;
    float* partial = (float*)d_ws;                       // 256 floats

    fused_luv_box<<<NBLK, 512, 0, stream>>>(inp, tgt, partial);
    finalize4<<<1, 256, 0, stream>>>(partial, out);
}